// Round 7
// baseline (5186.840 us; speedup 1.0000x reference)
//
#include <hip/hip_runtime.h>
#include <math.h>

#define BSZ 32
#define TT  32
#define XD  128
#define HD  512
#define VT  2048
#define ET  463
#define VKS 16

__device__ __forceinline__ float sigf(float x){ return 1.f/(1.f+expf(-x)); }
__device__ __forceinline__ float logsigf(float x){
    return (x >= 0.f) ? -log1pf(expf(-x)) : x - log1pf(expf(x));
}

// ---- 1024-thread block reductions (wave shfl + 16 partials; red[17+]) --------------
__device__ __forceinline__ float bsum(float v, float* red, int tid){
    #pragma unroll
    for (int off = 32; off > 0; off >>= 1) v += __shfl_xor(v, off);
    if ((tid & 63) == 0) red[tid >> 6] = v;
    __syncthreads();
    if (tid == 0){
        float s = red[0];
        #pragma unroll
        for (int i = 1; i < 16; ++i) s += red[i];
        red[16] = s;
    }
    __syncthreads();
    float r = red[16];
    __syncthreads();
    return r;
}
__device__ __forceinline__ float bmax(float v, float* red, int tid){
    #pragma unroll
    for (int off = 32; off > 0; off >>= 1) v = fmaxf(v, __shfl_xor(v, off));
    if ((tid & 63) == 0) red[tid >> 6] = v;
    __syncthreads();
    if (tid == 0){
        float s = red[0];
        #pragma unroll
        for (int i = 1; i < 16; ++i) s = fmaxf(s, red[i]);
        red[16] = s;
    }
    __syncthreads();
    float r = red[16];
    __syncthreads();
    return r;
}

// ---------------- batchnorm of x for ALL timesteps (recurrence-independent) ---------
__global__ void dnc_bnx(const float* __restrict__ x, float* __restrict__ bnx){
    int t = blockIdx.x, k = threadIdx.x;   // 128 threads
    float vals[BSZ];
    float s = 0.f;
    #pragma unroll
    for (int b = 0; b < BSZ; ++b){ vals[b] = x[(b*TT + t)*XD + k]; s += vals[b]; }
    float mean = s * (1.f/BSZ);
    float ss = 0.f;
    #pragma unroll
    for (int b = 0; b < BSZ; ++b){ float d = vals[b]-mean; ss += d*d; }
    float inv = 1.f / sqrtf(ss*(1.f/BSZ) + 1e-5f);
    #pragma unroll
    for (int b = 0; b < BSZ; ++b) bnx[((size_t)t*BSZ + b)*XD + k] = (vals[b]-mean)*inv;
}

// ---------------- fused LSTM: full-K GEMM + gates, register-prefetch staging ---------
// grid (64 u-chunks, 2 dirs), 256 thr. thread (b = tid&31, ui = tid>>5) owns all 4
// gates of (b, u = uc*8+ui). Chunk c+1 loaded into regs while chunk c computes.
__global__ __launch_bounds__(256) void dnc_lstm_fused(
    const float* __restrict__ srcA, int KA,
    const float* __restrict__ srcB, int KB,
    const float* __restrict__ hread,
    const float* __restrict__ Wih, const float* __restrict__ Whh,
    const float* __restrict__ bih, const float* __restrict__ bhh,
    float* __restrict__ cstate, float* __restrict__ hwrite,
    float* __restrict__ flat, float* __restrict__ lout, int l)
{
    const int uc = blockIdx.x, d = blockIdx.y;
    const int tid = threadIdx.x;
    const int b = tid & 31, ui = tid >> 5;
    const int u0 = uc*8;
    const int KIH = KA + KB;
    const int cA = KA >> 7;          // 128-wide chunks of srcA
    const int cin = KIH >> 7;        // end of input chunks
    const int nct = cin + 4;         // + HD/128 h-chunks
    __shared__ float itile[128*33];
    __shared__ __align__(16) float wtile[128*36];
    const float* WihD = Wih + (size_t)d*2048*KIH;
    const float* WhhD = Whh + (size_t)d*2048*512;
    const float* hD   = hread + d*(BSZ*HD);

    float ireg[16], wreg[16];
    auto loadchunk = [&](int c){
        const float* src; int stride, kb; const float* Wb; int Kw, wcol;
        if (c < cA){ src = srcA; stride = KA; kb = c*128; Wb = WihD; Kw = KIH; wcol = kb; }
        else if (c < cin){ src = srcB; stride = KB; kb = (c-cA)*128; Wb = WihD; Kw = KIH; wcol = c*128; }
        else { src = hD; stride = HD; kb = (c-cin)*128; Wb = WhhD; Kw = 512; wcol = kb; }
        #pragma unroll
        for (int i = 0; i < 16; ++i){
            int idx = i*256 + tid; int row = idx >> 7, kk = idx & 127;
            ireg[i] = src[row*stride + kb + kk];
            int j = (row & 3)*512 + u0 + (row >> 2);
            wreg[i] = Wb[(size_t)j*Kw + wcol + kk];
        }
    };

    float g0=0.f, g1=0.f, g2=0.f, g3=0.f;
    loadchunk(0);
    for (int c = 0; c < nct; ++c){
        #pragma unroll
        for (int i = 0; i < 16; ++i){
            int idx = i*256 + tid; int row = idx >> 7, kk = idx & 127;
            itile[kk*33 + row] = ireg[i];
            wtile[kk*36 + row] = wreg[i];
        }
        __syncthreads();
        if (c + 1 < nct) loadchunk(c + 1);   // in flight during compute below
        const int ui4 = ui*4;
        #pragma unroll 4
        for (int kk = 0; kk < 128; ++kk){
            float a = itile[kk*33 + b];
            float4 w = *(const float4*)&wtile[kk*36 + ui4];
            g0 += a*w.x; g1 += a*w.y; g2 += a*w.z; g3 += a*w.w;
        }
        __syncthreads();
    }
    const int u = u0 + ui;
    g0 += bih[d*2048 + u]        + bhh[d*2048 + u];
    g1 += bih[d*2048 + 512 + u]  + bhh[d*2048 + 512 + u];
    g2 += bih[d*2048 + 1024 + u] + bhh[d*2048 + 1024 + u];
    g3 += bih[d*2048 + 1536 + u] + bhh[d*2048 + 1536 + u];
    float ig = sigf(g0), fg = sigf(g1), og = sigf(g3), gg = tanhf(g2);
    int cell = 2*l + d;
    int ci = (cell*BSZ + b)*HD + u;
    float c2 = fg*cstate[ci] + ig*gg;
    cstate[ci] = c2;
    float h = og*tanhf(c2);
    hwrite[ci] = h;
    flat[b*2048 + cell*HD + u] = h;
    if (lout) lout[b*1024 + d*HD + u] = h;
}

// ---------------- combined GEMV: flat@Wy (bx 0-7, float4 weights) + flat@WE (bx 8-11) -
__global__ void dnc_gemv2(const float* __restrict__ fin, const float* __restrict__ Wy,
                          const float* __restrict__ WE,
                          float* __restrict__ vtp, float* __restrict__ ep){
    const int bx = blockIdx.x, ksi = blockIdx.y;
    const int tid = threadIdx.x;
    const int lane = tid & 63, bg = tid >> 6;
    const int b0 = bg*8;
    const int k0 = ksi*128;
    __shared__ __align__(16) float tile[128*36];
    #pragma unroll
    for (int i = 0; i < 16; ++i){
        int idx = i*256 + tid; int kk = idx & 127, b = idx >> 7;
        tile[kk*36 + b] = fin[b*2048 + k0 + kk];
    }
    __syncthreads();

    if (bx < 8){
        // ---- Wy path: lane owns 4 consecutive m; float4 weight loads ----
        const int m = bx*256 + lane*4;
        float acc[8][4] = {{0}};
        #pragma unroll 4
        for (int kk = 0; kk < 128; ++kk){
            float4 w  = *(const float4*)&Wy[(size_t)(k0+kk)*VT + m];
            float4 a0 = *(const float4*)&tile[kk*36 + b0];
            float4 a1 = *(const float4*)&tile[kk*36 + b0 + 4];
            acc[0][0]+=a0.x*w.x; acc[0][1]+=a0.x*w.y; acc[0][2]+=a0.x*w.z; acc[0][3]+=a0.x*w.w;
            acc[1][0]+=a0.y*w.x; acc[1][1]+=a0.y*w.y; acc[1][2]+=a0.y*w.z; acc[1][3]+=a0.y*w.w;
            acc[2][0]+=a0.z*w.x; acc[2][1]+=a0.z*w.y; acc[2][2]+=a0.z*w.z; acc[2][3]+=a0.z*w.w;
            acc[3][0]+=a0.w*w.x; acc[3][1]+=a0.w*w.y; acc[3][2]+=a0.w*w.z; acc[3][3]+=a0.w*w.w;
            acc[4][0]+=a1.x*w.x; acc[4][1]+=a1.x*w.y; acc[4][2]+=a1.x*w.z; acc[4][3]+=a1.x*w.w;
            acc[5][0]+=a1.y*w.x; acc[5][1]+=a1.y*w.y; acc[5][2]+=a1.y*w.z; acc[5][3]+=a1.y*w.w;
            acc[6][0]+=a1.z*w.x; acc[6][1]+=a1.z*w.y; acc[6][2]+=a1.z*w.z; acc[6][3]+=a1.z*w.w;
            acc[7][0]+=a1.w*w.x; acc[7][1]+=a1.w*w.y; acc[7][2]+=a1.w*w.z; acc[7][3]+=a1.w*w.w;
        }
        #pragma unroll
        for (int bb = 0; bb < 8; ++bb){
            float4 st = make_float4(acc[bb][0], acc[bb][1], acc[bb][2], acc[bb][3]);
            *(float4*)&vtp[((size_t)ksi*BSZ + b0+bb)*VT + m] = st;
        }
    } else {
        // ---- WE path (Mdim 463 odd -> scalar weights, 2 m per thread) ----
        const int mb = bx - 8;
        const int m0 = mb*128 + lane, m1 = m0 + 64;
        bool v0 = m0 < ET, v1 = m1 < ET;
        float acc[16] = {0};
        #pragma unroll 2
        for (int kk = 0; kk < 128; ++kk){
            float4 pq = *(const float4*)&tile[kk*36 + b0];
            float4 qq = *(const float4*)&tile[kk*36 + b0 + 4];
            const float* wr = WE + (size_t)(k0+kk)*ET;
            float w0 = v0 ? wr[m0] : 0.f;
            float w1 = v1 ? wr[m1] : 0.f;
            acc[0]+=pq.x*w0; acc[1]+=pq.y*w0; acc[2]+=pq.z*w0; acc[3]+=pq.w*w0;
            acc[4]+=qq.x*w0; acc[5]+=qq.y*w0; acc[6]+=qq.z*w0; acc[7]+=qq.w*w0;
            acc[8]+=pq.x*w1; acc[9]+=pq.y*w1; acc[10]+=pq.z*w1; acc[11]+=pq.w*w1;
            acc[12]+=qq.x*w1; acc[13]+=qq.y*w1; acc[14]+=qq.z*w1; acc[15]+=qq.w*w1;
        }
        if (v0){
            #pragma unroll
            for (int bb = 0; bb < 8; ++bb)
                ep[((size_t)ksi*BSZ + b0+bb)*ET + m0] = acc[bb];
        }
        if (v1){
            #pragma unroll
            for (int bb = 0; bb < 8; ++bb)
                ep[((size_t)ksi*BSZ + b0+bb)*ET + m1] = acc[8+bb];
        }
    }
}

// ---------------- presort (blocks 0-31) || cw_score (blocks 32-63) -------------------
__global__ __launch_bounds__(1024) void dnc_presort_cw(
    const float* __restrict__ ep, const float* __restrict__ lrw,
    const float* __restrict__ lww, float* __restrict__ ubuf,
    float* __restrict__ iv, float* __restrict__ allocw,
    const float* __restrict__ M, float* __restrict__ scw)
{
    const int bid = blockIdx.x, tid = threadIdx.x;
    const int lane = tid & 63, wid = tid >> 6;
    __shared__ float red[32];
    __shared__ float ivS[464];
    __shared__ unsigned long long keysS[1024];
    __shared__ float wtot[16], wpref[16];

    if (bid < 32){
        const int b = bid;
        // layernorm of WE partial sums -> iv
        float myv = 0.f;
        if (tid < ET){
            #pragma unroll
            for (int s = 0; s < VKS; ++s) myv += ep[((size_t)s*BSZ + b)*ET + tid];
        }
        float mean = bsum(myv, red, tid) * (1.f/ET);
        float dd = (tid < ET) ? (myv - mean) : 0.f;
        float var = bsum(dd*dd, red, tid) * (1.f/ET);
        float rinv = 1.f / sqrtf(var + 1e-5f);
        float ivv = (myv - mean)*rinv;
        if (tid < ET){ ivS[tid] = ivv; iv[b*ET + tid] = ivv; }
        __syncthreads();

        // usage
        const int n = tid;
        float4 lw4 = *(const float4*)&lrw[((size_t)b*1024 + n)*4];
        float f0 = sigf(ivS[453]), f1 = sigf(ivS[454]), f2 = sigf(ivS[455]), f3 = sigf(ivS[456]);
        float ret = (1.f-f0*lw4.x)*(1.f-f1*lw4.y)*(1.f-f2*lw4.z)*(1.f-f3*lw4.w);
        float uo = ubuf[b*1024+n], lwo = lww[b*1024+n];
        float un = (uo + lwo - uo*lwo)*ret;
        ubuf[b*1024+n] = un;

        // hybrid bitonic sort (LDS j>=64, shfl j<64); u>=0 so uint order == float order
        unsigned long long key = ((unsigned long long)__float_as_uint(un) << 32) | (unsigned)tid;
        for (int k = 2; k <= 1024; k <<= 1){
            int j = k >> 1;
            for (; j >= 64; j >>= 1){
                keysS[tid] = key; __syncthreads();
                unsigned long long other = keysS[tid ^ j];
                bool up = ((tid & k) == 0);
                bool takeMin = (((tid & j) == 0) == up);
                key = takeMin ? (key < other ? key : other) : (key > other ? key : other);
                __syncthreads();
            }
            for (; j >= 1; j >>= 1){
                unsigned long long other = __shfl_xor(key, j);
                bool up = ((tid & k) == 0);
                bool takeMin = (((tid & j) == 0) == up);
                key = takeMin ? (key < other ? key : other) : (key > other ? key : other);
            }
        }
        float su = __uint_as_float((unsigned)(key >> 32));
        int idxv = (int)(key & 0xffffffffu);

        // exclusive cumprod via wave shfl scan + 16 wave totals
        float p = su;
        #pragma unroll
        for (int o = 1; o < 64; o <<= 1){ float q = __shfl_up(p, o); if (lane >= o) p *= q; }
        if (lane == 63) wtot[wid] = p;
        __syncthreads();
        if (tid == 0){
            float r = 1.f;
            #pragma unroll
            for (int i = 0; i < 16; ++i){ wpref[i] = r; r *= wtot[i]; }
        }
        __syncthreads();
        float excl = __shfl_up(p, 1); if (lane == 0) excl = 1.f;
        float cpx = excl * wpref[wid];
        allocw[b*1024 + idxv] = (1.f - su)*cpx;
    } else {
        const int b = bid - 32;
        // mini-layernorm recompute (cheap; breaks same-stage dependency on iv)
        float myv = 0.f;
        if (tid < ET){
            #pragma unroll
            for (int s = 0; s < VKS; ++s) myv += ep[((size_t)s*BSZ + b)*ET + tid];
        }
        float mean = bsum(myv, red, tid) * (1.f/ET);
        float dd = (tid < ET) ? (myv - mean) : 0.f;
        float var = bsum(dd*dd, red, tid) * (1.f/ET);
        float rinv = 1.f / sqrtf(var + 1e-5f);
        float ivv = (myv - mean)*rinv;
        if (tid >= 260 && tid < 324) ivS[tid - 260] = ivv;   // write key
        if (tid == 324) ivS[64] = 1.f - logsigf(ivv);        // wbeta
        __syncthreads();
        float ksq = 0.f;
        #pragma unroll
        for (int w = 0; w < 64; ++w) ksq += ivS[w]*ivS[w];
        float kden = sqrtf(ksq) + 1e-8f;
        float wb = ivS[64];
        const float* Mrow = M + ((size_t)b*1024 + tid)*64;
        float dot = 0.f, msq = 0.f;
        #pragma unroll
        for (int w = 0; w < 64; w += 4){
            float4 mv = *(const float4*)(Mrow + w);
            dot += mv.x*ivS[w] + mv.y*ivS[w+1] + mv.z*ivS[w+2] + mv.w*ivS[w+3];
            msq += mv.x*mv.x + mv.y*mv.y + mv.z*mv.z + mv.w*mv.w;
        }
        scw[b*1024 + tid] = wb*dot/((sqrtf(msq) + 1e-8f)*kden);
    }
}

// ------- fused memory tail (32 blks x 1024): cw-softmax+ww, M update, read scores,
//         read softmax, read vectors. scr lives in LDS; M re-read via same-CU L1/L2. --
__global__ __launch_bounds__(1024) void dnc_memup_rv(
    float* __restrict__ M, const float* __restrict__ scw,
    const float* __restrict__ allocw, const float* __restrict__ iv,
    float* __restrict__ lww, float* __restrict__ lrw, float* __restrict__ lrv)
{
    const int b = blockIdx.x, tid = threadIdx.x;
    const int lane = tid & 63, wid = tid >> 6;
    __shared__ float red[32];
    __shared__ float aux[400];
    __shared__ float pS[4096];     // [r][n] scores then rw
    __shared__ float rvS[1024];
    const int n = tid;

    // ---- content-write softmax + ww ----
    float s = scw[b*1024 + n];
    float mx = bmax(s, red, tid);
    float tot = bsum(expf(s - mx), red, tid);
    float cwv = expf(s - mx)/tot;
    float ag = sigf(iv[b*ET + 457]), wg = sigf(iv[b*ET + 458]);
    float wwv = wg*(ag*allocw[b*1024 + n] + (1.f-ag)*cwv);
    lww[b*1024 + n] = wwv;

    // stage erase[0..63], wvec[64..127], rkn[128..383], nrm[384..387], rb[392..395]
    if (tid < 64){ aux[tid] = sigf(iv[b*ET + 325 + tid]); aux[64+tid] = iv[b*ET + 389 + tid]; }
    if (tid >= 64 && tid < 320) aux[64 + tid] = iv[b*ET + (tid - 64)];
    if (tid >= 320 && tid < 324) aux[72 + tid] = 1.f - logsigf(iv[b*ET + 256 + (tid - 320)]);
    __syncthreads();
    if (tid < 4){
        float ss = 0.f;
        #pragma unroll
        for (int w = 0; w < 64; ++w){ float v = aux[128 + w*4 + tid]; ss += v*v; }
        aux[384 + tid] = sqrtf(ss) + 1e-8f;
    }
    __syncthreads();
    if (tid < 256) aux[128 + tid] = aux[128 + tid] / aux[384 + (tid & 3)];
    __syncthreads();

    // ---- M update + read scores (scores -> LDS) ----
    float* Mrow = M + ((size_t)b*1024 + n)*64;
    float dr0=0.f, dr1=0.f, dr2=0.f, dr3=0.f, msq2=0.f;
    #pragma unroll
    for (int w = 0; w < 64; w += 4){
        float4 mv = *(const float4*)(Mrow + w);
        mv.x = mv.x*(1.f - wwv*aux[w+0]) + wwv*aux[64+w+0];
        mv.y = mv.y*(1.f - wwv*aux[w+1]) + wwv*aux[64+w+1];
        mv.z = mv.z*(1.f - wwv*aux[w+2]) + wwv*aux[64+w+2];
        mv.w = mv.w*(1.f - wwv*aux[w+3]) + wwv*aux[64+w+3];
        *(float4*)(Mrow + w) = mv;
        msq2 += mv.x*mv.x + mv.y*mv.y + mv.z*mv.z + mv.w*mv.w;
        dr0 += mv.x*aux[128+(w+0)*4+0] + mv.y*aux[128+(w+1)*4+0] + mv.z*aux[128+(w+2)*4+0] + mv.w*aux[128+(w+3)*4+0];
        dr1 += mv.x*aux[128+(w+0)*4+1] + mv.y*aux[128+(w+1)*4+1] + mv.z*aux[128+(w+2)*4+1] + mv.w*aux[128+(w+3)*4+1];
        dr2 += mv.x*aux[128+(w+0)*4+2] + mv.y*aux[128+(w+1)*4+2] + mv.z*aux[128+(w+2)*4+2] + mv.w*aux[128+(w+3)*4+2];
        dr3 += mv.x*aux[128+(w+0)*4+3] + mv.y*aux[128+(w+1)*4+3] + mv.z*aux[128+(w+2)*4+3] + mv.w*aux[128+(w+3)*4+3];
    }
    float den = sqrtf(msq2) + 1e-8f;
    pS[0*1024 + n] = aux[392]*dr0/den;
    pS[1*1024 + n] = aux[393]*dr1/den;
    pS[2*1024 + n] = aux[394]*dr2/den;
    pS[3*1024 + n] = aux[395]*dr3/den;
    __syncthreads();

    // ---- read softmax per r (r_ = tid>>8 owns 4 n) ----
    const int r_ = tid >> 8, i4 = (tid & 255)*4;
    float v0 = pS[r_*1024 + i4+0], v1 = pS[r_*1024 + i4+1];
    float v2 = pS[r_*1024 + i4+2], v3 = pS[r_*1024 + i4+3];
    float lm = fmaxf(fmaxf(v0,v1), fmaxf(v2,v3));
    #pragma unroll
    for (int off = 32; off > 0; off >>= 1) lm = fmaxf(lm, __shfl_xor(lm, off));
    if (lane == 0) red[wid] = lm;
    __syncthreads();
    if (tid < 4) red[16+tid] = fmaxf(fmaxf(red[4*tid],red[4*tid+1]), fmaxf(red[4*tid+2],red[4*tid+3]));
    __syncthreads();
    float mxr = red[16 + r_];
    float lsum = expf(v0-mxr) + expf(v1-mxr) + expf(v2-mxr) + expf(v3-mxr);
    #pragma unroll
    for (int off = 32; off > 0; off >>= 1) lsum += __shfl_xor(lsum, off);
    if (lane == 0) red[wid] = lsum;
    __syncthreads();
    if (tid < 4) red[20+tid] = red[4*tid]+red[4*tid+1]+red[4*tid+2]+red[4*tid+3];
    __syncthreads();
    float totr = red[20 + r_];
    {
        float w0 = expf(v0-mxr)/totr, w1 = expf(v1-mxr)/totr;
        float w2 = expf(v2-mxr)/totr, w3 = expf(v3-mxr)/totr;
        pS[r_*1024 + i4+0] = w0; pS[r_*1024 + i4+1] = w1;
        pS[r_*1024 + i4+2] = w2; pS[r_*1024 + i4+3] = w3;
        lrw[((size_t)(b*1024 + i4+0))*4 + r_] = w0;
        lrw[((size_t)(b*1024 + i4+1))*4 + r_] = w1;
        lrw[((size_t)(b*1024 + i4+2))*4 + r_] = w2;
        lrw[((size_t)(b*1024 + i4+3))*4 + r_] = w3;
    }
    __syncthreads();

    // ---- read vectors: thread (q = tid>>8, r = (tid>>6)&3, w = tid&63) ----
    {
        const int q = tid >> 8, r = (tid >> 6) & 3, w = tid & 63;
        const float* Mb = M + ((size_t)b*1024 + q*256)*64;
        const float* rb = pS + r*1024 + q*256;
        float acc = 0.f;
        for (int i = 0; i < 256; ++i)
            acc += Mb[(size_t)i*64 + w] * rb[i];
        rvS[tid] = acc;
    }
    __syncthreads();
    if (tid < 256){
        int w2 = tid >> 2, r2 = tid & 3;
        float ssum = 0.f;
        #pragma unroll
        for (int q = 0; q < 4; ++q) ssum += rvS[q*256 + r2*64 + w2];
        lrv[b*256 + tid] = ssum;     // layout [b][w*4+r]
    }
}

// ---------------- final: yt = lrv@Wr + sum(vtp); out = max over t --------------------
// grid (16 m-chunks, 4 b-groups) x 256 thr. thread: 4 m x 1 b.
__global__ void dnc_yfin(const float* __restrict__ lrv, const float* __restrict__ Wr,
                         const float* __restrict__ vtp, float* __restrict__ out, int t){
    const int tid = threadIdx.x;
    const int mg = tid & 31, bgl = tid >> 5;       // bgl 0..7
    const int m0 = blockIdx.x*128 + mg*4;
    const int b  = blockIdx.y*8 + bgl;
    __shared__ float lt[256*9];                    // lrv^T [k][bgl], pad 9
    #pragma unroll
    for (int i = 0; i < 8; ++i)
        lt[tid*9 + i] = lrv[((size_t)(blockIdx.y*8 + i))*256 + tid];
    __syncthreads();
    float4 acc = make_float4(0.f,0.f,0.f,0.f);
    for (int kk = 0; kk < 256; ++kk){
        float av = lt[kk*9 + bgl];
        float4 wv = *(const float4*)&Wr[(size_t)kk*VT + m0];
        acc.x += av*wv.x; acc.y += av*wv.y; acc.z += av*wv.z; acc.w += av*wv.w;
    }
    #pragma unroll
    for (int sp = 0; sp < VKS; ++sp){
        float4 vp = *(const float4*)&vtp[((size_t)sp*BSZ + b)*VT + m0];
        acc.x += vp.x; acc.y += vp.y; acc.z += vp.z; acc.w += vp.w;
    }
    float4* op = (float4*)&out[(size_t)b*VT + m0];
    if (t == 0){ *op = acc; }
    else {
        float4 cur = *op;
        cur.x = fmaxf(cur.x, acc.x); cur.y = fmaxf(cur.y, acc.y);
        cur.z = fmaxf(cur.z, acc.z); cur.w = fmaxf(cur.w, acc.w);
        *op = cur;
    }
}

extern "C" void kernel_launch(void* const* d_in, const int* in_sizes, int n_in,
                              void* d_out, int out_size, void* d_ws, size_t ws_size,
                              hipStream_t stream){
    const float* x      = (const float*)d_in[0];
    const float* mem0   = (const float*)d_in[1];
    const float* Wy     = (const float*)d_in[2];
    const float* WE     = (const float*)d_in[3];
    const float* Wr     = (const float*)d_in[4];
    const float* Wih0   = (const float*)d_in[5];
    const float* Whh0   = (const float*)d_in[6];
    const float* bih0   = (const float*)d_in[7];
    const float* bhh0   = (const float*)d_in[8];
    const float* Wih1   = (const float*)d_in[9];
    const float* Whh1   = (const float*)d_in[10];
    const float* bih1   = (const float*)d_in[11];
    const float* bhh1   = (const float*)d_in[12];
    float* out = (float*)d_out;

    float* p = (float*)d_ws;
    float* M       = p; p += (size_t)BSZ*1024*64;
    float* hstate0 = p; p += 4*BSZ*HD;     // zero block start
    float* hstate1 = p; p += 4*BSZ*HD;
    float* cstate  = p; p += 4*BSZ*HD;
    float* ubuf    = p; p += BSZ*1024;
    float* lww     = p; p += BSZ*1024;
    float* lrw     = p; p += BSZ*1024*4;
    float* lrv     = p; p += BSZ*256;      // zero block end
    float* bnx     = p; p += (size_t)TT*BSZ*XD;
    float* lin1    = p; p += BSZ*1024;
    float* flat    = p; p += BSZ*2048;
    float* vtp     = p; p += (size_t)VKS*BSZ*VT;
    float* ep      = p; p += (size_t)VKS*BSZ*ET;
    float* iv      = p; p += BSZ*ET;
    float* allocw  = p; p += BSZ*1024;
    float* scw     = p; p += BSZ*1024;

    (void)hipMemcpyAsync(M, mem0, (size_t)BSZ*1024*64*sizeof(float), hipMemcpyDeviceToDevice, stream);
    size_t zfloats = (size_t)(4*BSZ*HD)*3 + BSZ*1024*2 + BSZ*1024*4 + BSZ*256;
    (void)hipMemsetAsync(hstate0, 0, zfloats*sizeof(float), stream);

    dnc_bnx<<<TT, 128, 0, stream>>>(x, bnx);

    for (int t = 0; t < TT; ++t){
        const float* hr = (t & 1) ? hstate1 : hstate0;
        float*       hw = (t & 1) ? hstate0 : hstate1;
        dnc_lstm_fused<<<dim3(64,2), 256, 0, stream>>>(bnx + (size_t)t*BSZ*XD, XD,
            lrv, 256, hr, Wih0, Whh0, bih0, bhh0, cstate, hw, flat, lin1, 0);
        dnc_lstm_fused<<<dim3(64,2), 256, 0, stream>>>(lin1, 1024,
            nullptr, 0, hr + 2*BSZ*HD, Wih1, Whh1, bih1, bhh1, cstate, hw, flat, nullptr, 1);
        dnc_gemv2<<<dim3(12,VKS), 256, 0, stream>>>(flat, Wy, WE, vtp, ep);
        dnc_presort_cw<<<64, 1024, 0, stream>>>(ep, lrw, lww, ubuf, iv, allocw, M, scw);
        dnc_memup_rv<<<32, 1024, 0, stream>>>(M, scw, allocw, iv, lww, lrw, lrv);
        dnc_yfin<<<dim3(16,4), 256, 0, stream>>>(lrv, Wr, vtp, out, t);
    }
}